// Round 6
// baseline (112.025 us; speedup 1.0000x reference)
//
#include <hip/hip_runtime.h>
#include <hip/hip_bf16.h>

// out[b,m,n] = sum_k fq(x1)[b,m,k] * fq(x2)[b,k,n], B=8 M=4096 K=64 N=4096.
// fq maps every value to code/255, code in [0,255] -> codes exact in bf16.
// kernel1 (merged): quantize A (straight) + B (transposed -> [n][k]) once.
// kernel2: LDS-staged 128x128 MFMA GEMM with XCD-aware block swizzle:
// 8192 blocks, swz=(id%8)*1024+id/8 -> XCD x owns batch x entirely
// (1MB codes L2-resident, 64MB contiguous write region per XCD).
// Write-bound: 512MB f32 out ~76us at 6.7TB/s measured fill BW.

#define BATCH 8
#define MDIM 4096
#define KDIM 64
#define NDIM 4096

typedef __attribute__((ext_vector_type(4))) unsigned short u16x4;
typedef __attribute__((ext_vector_type(8))) short s16x8;
typedef __attribute__((ext_vector_type(4))) float f32x4;

// quantize x -> integer code (0..level-1) as bf16 bit pattern (exact:
// integers 0..255 have zero low-mantissa bits in f32)
__device__ __forceinline__ unsigned short qcode(float x, float c, float inv) {
    float xc = fminf(fmaxf(x, 0.0f), c);
    float k = rintf(xc * inv);            // round-half-even == np.round
    return (unsigned short)(__float_as_uint(k) >> 16);
}

// ---- kernel 1: quantize A [B,M,K]->codes (same layout), and B [B,K,N] ->
// codes transposed [B,N,K]. Block-range dispatch: first QA_BLOCKS blocks do
// A (pure elementwise), the rest do 64x64 B tiles through LDS.
#define QA_BLOCKS 2048   // 2M f32 elems / (256 thr * 4 elems)

__global__ void quant_both(const float* __restrict__ x1, const float* __restrict__ x2,
                           unsigned short* __restrict__ qA, unsigned short* __restrict__ qBt,
                           const float* __restrict__ c1p, const float* __restrict__ c2p,
                           const int* __restrict__ lvp) {
    __shared__ unsigned short T[64 * 68];   // B path only; pad 68 spreads banks
    const int t = threadIdx.x;
    const float lvm1 = (float)(lvp[0] - 1);

    if (blockIdx.x < QA_BLOCKS) {
        // ---- A path: x1 f32 -> bf16 codes, 1 float4 per thread
        const float c = c1p[0], inv = lvm1 / c;
        int i = blockIdx.x * 256 + t;
        float4 v = ((const float4*)x1)[i];
        u16x4 o;
        o[0] = qcode(v.x, c, inv);
        o[1] = qcode(v.y, c, inv);
        o[2] = qcode(v.z, c, inv);
        o[3] = qcode(v.w, c, inv);
        ((u16x4*)qA)[i] = o;
        return;
    }

    // ---- B path: quantize + transpose one [64 k][64 n] tile
    const float c = c2p[0], inv = lvm1 / c;
    int bi = blockIdx.x - QA_BLOCKS;        // [0, 512)
    int b = bi >> 6;                        // batch
    int n0 = (bi & 63) * 64;                // n tile origin

    const float* src = x2 + (size_t)b * KDIM * NDIM + n0;
#pragma unroll
    for (int it = 0; it < 4; ++it) {
        int qi = t + it * 256;
        int k = qi >> 4, c4 = qi & 15;      // 64 rows x 16 float4
        float4 v = *(const float4*)(src + (size_t)k * NDIM + c4 * 4);
        u16x4 o;
        o[0] = qcode(v.x, c, inv);
        o[1] = qcode(v.y, c, inv);
        o[2] = qcode(v.z, c, inv);
        o[3] = qcode(v.w, c, inv);
        *(u16x4*)&T[k * 68 + c4 * 4] = o;
    }
    __syncthreads();

    unsigned short* dst = qBt + ((size_t)b * NDIM + n0) * KDIM;
#pragma unroll
    for (int it = 0; it < 4; ++it) {
        int qi = t + it * 256;
        int n = qi >> 4, c4 = qi & 15;      // 64 out-rows x 16 chunks of 4 k
        u16x4 o;
        o[0] = T[(c4 * 4 + 0) * 68 + n];
        o[1] = T[(c4 * 4 + 1) * 68 + n];
        o[2] = T[(c4 * 4 + 2) * 68 + n];
        o[3] = T[(c4 * 4 + 3) * 68 + n];
        *(u16x4*)(dst + (size_t)n * KDIM + c4 * 4) = o;
    }
}

// ---- kernel 2: GEMM. 128x128 tile, full K=64 staged once in LDS
// (XOR-swizzled), 4 waves (2x2), each wave 64x64 via 4x4 fragments of
// 16x16x32 bf16 MFMA. Plain dword stores. XCD-aware block swizzle.
__global__ __launch_bounds__(256)
void gemm_q(const unsigned short* __restrict__ qA, const unsigned short* __restrict__ qBt,
            const float* __restrict__ c1p, const float* __restrict__ c2p,
            const int* __restrict__ lvp, float* __restrict__ out) {
    __shared__ unsigned short As[128 * 64];   // [m][k] codes, XOR-swizzled
    __shared__ unsigned short Bs[128 * 64];   // [n][k] codes, XOR-swizzled

    // XCD swizzle: 8192 blocks, 8 XCDs, 8192%8==0 -> bijective chunk map.
    // XCD x gets orig%8==x -> swz in [x*1024,(x+1)*1024) -> b==x: each XCD
    // owns one batch (codes L2-resident, contiguous 64MB write region).
    const int orig = blockIdx.x;
    const int swz = (orig & 7) * 1024 + (orig >> 3);
    const int nt = swz & 31, mt = (swz >> 5) & 31, b = swz >> 10;
    const int t = threadIdx.x;

    const unsigned short* gA = qA + ((size_t)b * MDIM + mt * 128) * KDIM;
    const unsigned short* gB = qBt + ((size_t)b * NDIM + nt * 128) * KDIM;

    // stage both tiles: 128 rows x 128B, 16B per thread-iter, swizzle rows
#pragma unroll
    for (int it = 0; it < 4; ++it) {
        int qi = t + it * 256;
        int row = qi >> 3, c8 = qi & 7;
        s16x8 va = *(const s16x8*)(gA + (size_t)row * KDIM + c8 * 8);
        s16x8 vb = *(const s16x8*)(gB + (size_t)row * KDIM + c8 * 8);
        int off = (row * 128 + c8 * 16) ^ ((row & 7) << 4);
        *(s16x8*)((char*)As + off) = va;
        *(s16x8*)((char*)Bs + off) = vb;
    }
    __syncthreads();

    const int lane = t & 63, w = t >> 6;
    const int wr = (w >> 1) * 64, wc = (w & 1) * 64;   // wave 64x64 sub-tile
    const int r16 = lane & 15, kq = lane >> 4;

    f32x4 acc[4][4] = {};
#pragma unroll
    for (int ks = 0; ks < 2; ++ks) {
        const int kb = ks * 64 + kq * 16;   // byte offset of lane's k-slice
        s16x8 a[4], bf[4];
#pragma unroll
        for (int mf = 0; mf < 4; ++mf) {
            int row = wr + mf * 16 + r16;
            int off = (row * 128 + kb) ^ ((row & 7) << 4);
            a[mf] = *(const s16x8*)((const char*)As + off);
        }
#pragma unroll
        for (int nf = 0; nf < 4; ++nf) {
            int row = wc + nf * 16 + r16;
            int off = (row * 128 + kb) ^ ((row & 7) << 4);
            bf[nf] = *(const s16x8*)((const char*)Bs + off);
        }
#pragma unroll
        for (int mf = 0; mf < 4; ++mf)
#pragma unroll
            for (int nf = 0; nf < 4; ++nf)
                acc[mf][nf] = __builtin_amdgcn_mfma_f32_16x16x32_bf16(
                    a[mf], bf[nf], acc[mf][nf], 0, 0, 0);
    }

    // epilogue: scale integer-code accum, plain dword stores (L2 combines)
    const float c1 = c1p[0], c2 = c2p[0];
    const float lvm1 = (float)(lvp[0] - 1);
    const float s = (c1 / lvm1) * (c2 / lvm1);

    size_t obase = (size_t)b * MDIM * NDIM;
    int m0 = mt * 128 + wr, n0 = nt * 128 + wc;
#pragma unroll
    for (int mf = 0; mf < 4; ++mf) {
#pragma unroll
        for (int i = 0; i < 4; ++i) {
            int m = m0 + mf * 16 + kq * 4 + i;
            float* orow = out + obase + (size_t)m * NDIM + n0 + r16;
#pragma unroll
            for (int nf = 0; nf < 4; ++nf)
                orow[nf * 16] = acc[mf][nf][i] * s;
        }
    }
}

extern "C" void kernel_launch(void* const* d_in, const int* in_sizes, int n_in,
                              void* d_out, int out_size, void* d_ws, size_t ws_size,
                              hipStream_t stream) {
    const float* x1 = (const float*)d_in[0];
    const float* x2 = (const float*)d_in[1];
    const float* c1 = (const float*)d_in[2];
    const float* c2 = (const float*)d_in[3];
    const int* lv   = (const int*)d_in[4];
    float* out = (float*)d_out;

    // workspace: qA codes 4MB @ 0, qB^T codes 4MB @ +4MB (needs ws >= 8MB)
    unsigned short* qA = (unsigned short*)d_ws;
    unsigned short* qB = qA + (size_t)BATCH * MDIM * KDIM;

    quant_both<<<QA_BLOCKS + BATCH * (NDIM / 64), 256, 0, stream>>>(
        x1, x2, qA, qB, c1, c2, lv);
    gemm_q<<<8192, 256, 0, stream>>>(qA, qB, c1, c2, lv, out);
}

// Round 7
// 107.856 us; speedup vs baseline: 1.0387x; 1.0387x over previous
//
#include <hip/hip_runtime.h>
#include <hip/hip_bf16.h>

// out[b,m,n] = sum_k fq(x1)[b,m,k] * fq(x2)[b,k,n], B=8 M=4096 K=64 N=4096.
// fq maps every value to code/255, code in [0,255] -> codes exact in bf16.
// kernel1 (merged): quantize A (straight) + B (transposed -> [n][k]) once.
// kernel2: LDS-staged 128x128 MFMA GEMM; epilogue repacks acc through LDS
// (reusing As/Bs after a barrier) so every global store is dwordx4 with
// 512B-contiguous row segments (full 128B lines -> long HBM write bursts).
// Write-bound: 512MB f32 out ~76us at 6.7TB/s measured fill BW.

#define BATCH 8
#define MDIM 4096
#define KDIM 64
#define NDIM 4096

typedef __attribute__((ext_vector_type(4))) unsigned short u16x4;
typedef __attribute__((ext_vector_type(8))) short s16x8;
typedef __attribute__((ext_vector_type(4))) float f32x4;

// quantize x -> integer code (0..level-1) as bf16 bit pattern (exact:
// integers 0..255 have zero low-mantissa bits in f32)
__device__ __forceinline__ unsigned short qcode(float x, float c, float inv) {
    float xc = fminf(fmaxf(x, 0.0f), c);
    float k = rintf(xc * inv);            // round-half-even == np.round
    return (unsigned short)(__float_as_uint(k) >> 16);
}

// ---- kernel 1: quantize A [B,M,K]->codes (same layout), and B [B,K,N] ->
// codes transposed [B,N,K]. Block-range dispatch: first QA_BLOCKS blocks do
// A (pure elementwise), the rest do 64x64 B tiles through LDS.
#define QA_BLOCKS 2048   // 2M f32 elems / (256 thr * 4 elems)

__global__ void quant_both(const float* __restrict__ x1, const float* __restrict__ x2,
                           unsigned short* __restrict__ qA, unsigned short* __restrict__ qBt,
                           const float* __restrict__ c1p, const float* __restrict__ c2p,
                           const int* __restrict__ lvp) {
    __shared__ unsigned short T[64 * 68];   // B path only; pad 68 spreads banks
    const int t = threadIdx.x;
    const float lvm1 = (float)(lvp[0] - 1);

    if (blockIdx.x < QA_BLOCKS) {
        // ---- A path: x1 f32 -> bf16 codes, 1 float4 per thread
        const float c = c1p[0], inv = lvm1 / c;
        int i = blockIdx.x * 256 + t;
        float4 v = ((const float4*)x1)[i];
        u16x4 o;
        o[0] = qcode(v.x, c, inv);
        o[1] = qcode(v.y, c, inv);
        o[2] = qcode(v.z, c, inv);
        o[3] = qcode(v.w, c, inv);
        ((u16x4*)qA)[i] = o;
        return;
    }

    // ---- B path: quantize + transpose one [64 k][64 n] tile
    const float c = c2p[0], inv = lvm1 / c;
    int bi = blockIdx.x - QA_BLOCKS;        // [0, 512)
    int b = bi >> 6;                        // batch
    int n0 = (bi & 63) * 64;                // n tile origin

    const float* src = x2 + (size_t)b * KDIM * NDIM + n0;
#pragma unroll
    for (int it = 0; it < 4; ++it) {
        int qi = t + it * 256;
        int k = qi >> 4, c4 = qi & 15;      // 64 rows x 16 float4
        float4 v = *(const float4*)(src + (size_t)k * NDIM + c4 * 4);
        u16x4 o;
        o[0] = qcode(v.x, c, inv);
        o[1] = qcode(v.y, c, inv);
        o[2] = qcode(v.z, c, inv);
        o[3] = qcode(v.w, c, inv);
        *(u16x4*)&T[k * 68 + c4 * 4] = o;
    }
    __syncthreads();

    unsigned short* dst = qBt + ((size_t)b * NDIM + n0) * KDIM;
#pragma unroll
    for (int it = 0; it < 4; ++it) {
        int qi = t + it * 256;
        int n = qi >> 4, c4 = qi & 15;      // 64 out-rows x 16 chunks of 4 k
        u16x4 o;
        o[0] = T[(c4 * 4 + 0) * 68 + n];
        o[1] = T[(c4 * 4 + 1) * 68 + n];
        o[2] = T[(c4 * 4 + 2) * 68 + n];
        o[3] = T[(c4 * 4 + 3) * 68 + n];
        *(u16x4*)(dst + (size_t)n * KDIM + c4 * 4) = o;
    }
}

// ---- kernel 2: GEMM. 128x128 tile, full K=64 staged once in LDS
// (XOR-swizzled), 4 waves (2x2), each wave 64x64 via 4x4 fragments of
// 16x16x32 bf16 MFMA. Epilogue: repack acc through LDS (reuse As/Bs),
// store dwordx4 with 512B-contiguous rows.
__global__ __launch_bounds__(256)
void gemm_q(const unsigned short* __restrict__ qA, const unsigned short* __restrict__ qBt,
            const float* __restrict__ c1p, const float* __restrict__ c2p,
            const int* __restrict__ lvp, float* __restrict__ out) {
    __shared__ __align__(16) unsigned char smem[32768];
    unsigned short* As = (unsigned short*)smem;            // [128][64] codes
    unsigned short* Bs = (unsigned short*)(smem + 16384);  // [128][64] codes
    float* R = (float*)smem;                               // epilogue reuse

    const int b = blockIdx.z, mt = blockIdx.y, nt = blockIdx.x;
    const int t = threadIdx.x;

    const unsigned short* gA = qA + ((size_t)b * MDIM + mt * 128) * KDIM;
    const unsigned short* gB = qBt + ((size_t)b * NDIM + nt * 128) * KDIM;

    // stage both tiles: 128 rows x 128B, 16B per thread-iter, swizzle rows
#pragma unroll
    for (int it = 0; it < 4; ++it) {
        int qi = t + it * 256;
        int row = qi >> 3, c8 = qi & 7;
        s16x8 va = *(const s16x8*)(gA + (size_t)row * KDIM + c8 * 8);
        s16x8 vb = *(const s16x8*)(gB + (size_t)row * KDIM + c8 * 8);
        int off = (row * 128 + c8 * 16) ^ ((row & 7) << 4);
        *(s16x8*)((char*)As + off) = va;
        *(s16x8*)((char*)Bs + off) = vb;
    }
    __syncthreads();

    const int lane = t & 63, w = t >> 6;
    const int wr = (w >> 1) * 64, wc = (w & 1) * 64;   // wave 64x64 sub-tile
    const int r16 = lane & 15, kq = lane >> 4;

    f32x4 acc[4][4] = {};
#pragma unroll
    for (int ks = 0; ks < 2; ++ks) {
        const int kb = ks * 64 + kq * 16;   // byte offset of lane's k-slice
        s16x8 a[4], bf[4];
#pragma unroll
        for (int mf = 0; mf < 4; ++mf) {
            int row = wr + mf * 16 + r16;
            int off = (row * 128 + kb) ^ ((row & 7) << 4);
            a[mf] = *(const s16x8*)((const char*)As + off);
        }
#pragma unroll
        for (int nf = 0; nf < 4; ++nf) {
            int row = wc + nf * 16 + r16;
            int off = (row * 128 + kb) ^ ((row & 7) << 4);
            bf[nf] = *(const s16x8*)((const char*)Bs + off);
        }
#pragma unroll
        for (int mf = 0; mf < 4; ++mf)
#pragma unroll
            for (int nf = 0; nf < 4; ++nf)
                acc[mf][nf] = __builtin_amdgcn_mfma_f32_16x16x32_bf16(
                    a[mf], bf[nf], acc[mf][nf], 0, 0, 0);
    }
    __syncthreads();   // all LDS reads done -> safe to reuse As/Bs as R

    // ---- epilogue: 2 passes; each repacks 64 rows x 128 cols f32 (32KB)
    // through LDS, then stores dwordx4 (2 x 512B contiguous rows / instr).
    // D mapping (normal operand order): m = kq*4+i (+mf*16+wr), n = r16
    // (+nf*16+wc). Local row lr = (wr/2) + mfp*16 + kq*4 + i in [0,64).
    const float c1 = c1p[0], c2 = c2p[0];
    const float lvm1 = (float)(lvp[0] - 1);
    const float s = (c1 / lvm1) * (c2 / lvm1);
    const size_t obase = (size_t)b * MDIM * NDIM;
    const int m0blk = mt * 128, n0blk = nt * 128;

#pragma unroll
    for (int p = 0; p < 2; ++p) {
        // write: scaled acc -> R, XOR-swizzled (2-way banks max = free)
#pragma unroll
        for (int mfp = 0; mfp < 2; ++mfp) {
            int mf = 2 * p + mfp;
            int lrb = (wr >> 1) + mfp * 16 + kq * 4;
#pragma unroll
            for (int nf = 0; nf < 4; ++nf) {
                int col = wc + nf * 16 + r16;
#pragma unroll
                for (int i = 0; i < 4; ++i) {
                    int lr = lrb + i;
                    int byte = (lr * 512 + col * 4) ^ ((lr & 7) << 4);
                    *(float*)((char*)R + byte) = acc[mf][nf][i] * s;
                }
            }
        }
        __syncthreads();

        // read + store: wave w owns rows [w*16, w*16+16); 2 rows per instr
#pragma unroll
        for (int j = 0; j < 8; ++j) {
            int lr = w * 16 + 2 * j + (lane >> 5);
            int byte = (lr * 512 + (lane & 31) * 16) ^ ((lr & 7) << 4);
            f32x4 v = *(const f32x4*)((const char*)R + byte);
            // decode lr -> block row: g=lr>>5, mf'=(lr>>4)&1, sub=lr&15
            int br = ((lr >> 5) << 6) + (2 * p + ((lr >> 4) & 1)) * 16 + (lr & 15);
            float* dst = out + obase + (size_t)(m0blk + br) * NDIM
                       + n0blk + (lane & 31) * 4;
            *(f32x4*)dst = v;
        }
        __syncthreads();   // pass-0 reads done before pass-1 overwrites
    }
}

extern "C" void kernel_launch(void* const* d_in, const int* in_sizes, int n_in,
                              void* d_out, int out_size, void* d_ws, size_t ws_size,
                              hipStream_t stream) {
    const float* x1 = (const float*)d_in[0];
    const float* x2 = (const float*)d_in[1];
    const float* c1 = (const float*)d_in[2];
    const float* c2 = (const float*)d_in[3];
    const int* lv   = (const int*)d_in[4];
    float* out = (float*)d_out;

    // workspace: qA codes 4MB @ 0, qB^T codes 4MB @ +4MB (needs ws >= 8MB)
    unsigned short* qA = (unsigned short*)d_ws;
    unsigned short* qB = qA + (size_t)BATCH * MDIM * KDIM;

    quant_both<<<QA_BLOCKS + BATCH * (NDIM / 64), 256, 0, stream>>>(
        x1, x2, qA, qB, c1, c2, lv);
    gemm_q<<<dim3(NDIM / 128, MDIM / 128, BATCH), 256, 0, stream>>>(
        qA, qB, c1, c2, lv, out);
}

// Round 8
// 107.649 us; speedup vs baseline: 1.0407x; 1.0019x over previous
//
#include <hip/hip_runtime.h>
#include <hip/hip_bf16.h>

// out[b,m,n] = sum_k fq(x1)[b,m,k] * fq(x2)[b,k,n], B=8 M=4096 K=64 N=4096.
// fq maps every value to code/255, code in [0,255] -> codes exact in bf16.
// kernel1 (merged): quantize A (straight) + B (transposed -> [n][k]) once.
// kernel2: LDS-staged 64x256 MFMA GEMM; epilogue repacks acc through LDS so
// every global store is one FULL output row segment of 1024B (wave-wide
// dwordx4, fill-kernel-shaped bursts). Write-bound: 512MB f32 out ~76us.

#define BATCH 8
#define MDIM 4096
#define KDIM 64
#define NDIM 4096

typedef __attribute__((ext_vector_type(4))) unsigned short u16x4;
typedef __attribute__((ext_vector_type(8))) short s16x8;
typedef __attribute__((ext_vector_type(4))) float f32x4;

// quantize x -> integer code (0..level-1) as bf16 bit pattern (exact:
// integers 0..255 have zero low-mantissa bits in f32)
__device__ __forceinline__ unsigned short qcode(float x, float c, float inv) {
    float xc = fminf(fmaxf(x, 0.0f), c);
    float k = rintf(xc * inv);            // round-half-even == np.round
    return (unsigned short)(__float_as_uint(k) >> 16);
}

// ---- kernel 1: quantize A [B,M,K]->codes (same layout), and B [B,K,N] ->
// codes transposed [B,N,K]. Block-range dispatch: first QA_BLOCKS blocks do
// A (pure elementwise), the rest do 64x64 B tiles through LDS.
#define QA_BLOCKS 2048   // 2M f32 elems / (256 thr * 4 elems)

__global__ void quant_both(const float* __restrict__ x1, const float* __restrict__ x2,
                           unsigned short* __restrict__ qA, unsigned short* __restrict__ qBt,
                           const float* __restrict__ c1p, const float* __restrict__ c2p,
                           const int* __restrict__ lvp) {
    __shared__ unsigned short T[64 * 68];   // B path only; pad 68 spreads banks
    const int t = threadIdx.x;
    const float lvm1 = (float)(lvp[0] - 1);

    if (blockIdx.x < QA_BLOCKS) {
        // ---- A path: x1 f32 -> bf16 codes, 1 float4 per thread
        const float c = c1p[0], inv = lvm1 / c;
        int i = blockIdx.x * 256 + t;
        float4 v = ((const float4*)x1)[i];
        u16x4 o;
        o[0] = qcode(v.x, c, inv);
        o[1] = qcode(v.y, c, inv);
        o[2] = qcode(v.z, c, inv);
        o[3] = qcode(v.w, c, inv);
        ((u16x4*)qA)[i] = o;
        return;
    }

    // ---- B path: quantize + transpose one [64 k][64 n] tile
    const float c = c2p[0], inv = lvm1 / c;
    int bi = blockIdx.x - QA_BLOCKS;        // [0, 512)
    int b = bi >> 6;                        // batch
    int n0 = (bi & 63) * 64;                // n tile origin

    const float* src = x2 + (size_t)b * KDIM * NDIM + n0;
#pragma unroll
    for (int it = 0; it < 4; ++it) {
        int qi = t + it * 256;
        int k = qi >> 4, c4 = qi & 15;      // 64 rows x 16 float4
        float4 v = *(const float4*)(src + (size_t)k * NDIM + c4 * 4);
        u16x4 o;
        o[0] = qcode(v.x, c, inv);
        o[1] = qcode(v.y, c, inv);
        o[2] = qcode(v.z, c, inv);
        o[3] = qcode(v.w, c, inv);
        *(u16x4*)&T[k * 68 + c4 * 4] = o;
    }
    __syncthreads();

    unsigned short* dst = qBt + ((size_t)b * NDIM + n0) * KDIM;
#pragma unroll
    for (int it = 0; it < 4; ++it) {
        int qi = t + it * 256;
        int n = qi >> 4, c4 = qi & 15;      // 64 out-rows x 16 chunks of 4 k
        u16x4 o;
        o[0] = T[(c4 * 4 + 0) * 68 + n];
        o[1] = T[(c4 * 4 + 1) * 68 + n];
        o[2] = T[(c4 * 4 + 2) * 68 + n];
        o[3] = T[(c4 * 4 + 3) * 68 + n];
        *(u16x4*)(dst + (size_t)n * KDIM + c4 * 4) = o;
    }
}

// ---- kernel 2: GEMM. 64x256 tile, full K=64 staged once in LDS
// (XOR-swizzled). 4 waves in 1x4: wave w owns n-slice [w*64, w*64+64),
// all 64 m rows -> 4x4 fragments of 16x16x32 bf16 MFMA. Epilogue: repack
// acc through LDS (reuse Bs), store FULL 1KB rows per wave instruction.
__global__ __launch_bounds__(256)
void gemm_q(const unsigned short* __restrict__ qA, const unsigned short* __restrict__ qBt,
            const float* __restrict__ c1p, const float* __restrict__ c2p,
            const int* __restrict__ lvp, float* __restrict__ out) {
    __shared__ __align__(16) unsigned char smem[40960];
    unsigned short* As = (unsigned short*)smem;            // [64][64] codes, 8KB
    unsigned short* Bs = (unsigned short*)(smem + 8192);   // [256][64] codes, 32KB
    float* R = (float*)(smem + 8192);                      // epilogue reuse, 32KB

    const int b = blockIdx.z, mt = blockIdx.y, nt = blockIdx.x;
    const int t = threadIdx.x;

    const unsigned short* gA = qA + ((size_t)b * MDIM + mt * 64) * KDIM;
    const unsigned short* gB = qBt + ((size_t)b * NDIM + nt * 256) * KDIM;

    // stage A: 64 rows x 128B (2 x 16B per thread), swizzled
#pragma unroll
    for (int it = 0; it < 2; ++it) {
        int qi = t + it * 256;
        int row = qi >> 3, c8 = qi & 7;
        s16x8 va = *(const s16x8*)(gA + (size_t)row * KDIM + c8 * 8);
        int off = (row * 128 + c8 * 16) ^ ((row & 7) << 4);
        *(s16x8*)((char*)As + off) = va;
    }
    // stage B: 256 rows x 128B (8 x 16B per thread), swizzled
#pragma unroll
    for (int it = 0; it < 8; ++it) {
        int qi = t + it * 256;
        int row = qi >> 3, c8 = qi & 7;
        s16x8 vb = *(const s16x8*)(gB + (size_t)row * KDIM + c8 * 8);
        int off = (row * 128 + c8 * 16) ^ ((row & 7) << 4);
        *(s16x8*)((char*)Bs + off) = vb;
    }
    __syncthreads();

    const int lane = t & 63, w = t >> 6;
    const int r16 = lane & 15, kq = lane >> 4;

    f32x4 acc[4][4] = {};
#pragma unroll
    for (int ks = 0; ks < 2; ++ks) {
        const int kb = ks * 64 + kq * 16;   // byte offset of lane's k-slice
        s16x8 a[4], bf[4];
#pragma unroll
        for (int mf = 0; mf < 4; ++mf) {
            int row = mf * 16 + r16;
            int off = (row * 128 + kb) ^ ((row & 7) << 4);
            a[mf] = *(const s16x8*)((const char*)As + off);
        }
#pragma unroll
        for (int nf = 0; nf < 4; ++nf) {
            int row = w * 64 + nf * 16 + r16;
            int off = (row * 128 + kb) ^ ((row & 7) << 4);
            bf[nf] = *(const s16x8*)((const char*)Bs + off);
        }
#pragma unroll
        for (int mf = 0; mf < 4; ++mf)
#pragma unroll
            for (int nf = 0; nf < 4; ++nf)
                acc[mf][nf] = __builtin_amdgcn_mfma_f32_16x16x32_bf16(
                    a[mf], bf[nf], acc[mf][nf], 0, 0, 0);
    }
    __syncthreads();   // all LDS reads done -> safe to reuse Bs as R

    // ---- epilogue: 2 passes of 32 rows x 256 cols f32 (32KB) through R;
    // each store instr = one full row = 1024B contiguous.
    // acc[mf][nf][i]: m = mf*16 + kq*4 + i, n_rel = w*64 + nf*16 + r16.
    const float c1 = c1p[0], c2 = c2p[0];
    const float lvm1 = (float)(lvp[0] - 1);
    const float s = (c1 / lvm1) * (c2 / lvm1);
    const size_t obase = (size_t)b * MDIM * NDIM;
    const int m0blk = mt * 64, n0blk = nt * 256;

#pragma unroll
    for (int p = 0; p < 2; ++p) {
        // write: scaled acc (m in [p*32, p*32+32)) -> R, XOR-swizzled
#pragma unroll
        for (int mfp = 0; mfp < 2; ++mfp) {
            int mf = 2 * p + mfp;
#pragma unroll
            for (int nf = 0; nf < 4; ++nf) {
                int n_rel = w * 64 + nf * 16 + r16;
#pragma unroll
                for (int i = 0; i < 4; ++i) {
                    int lr = mfp * 16 + kq * 4 + i;       // [0,32)
                    int byte = (lr * 1024 + n_rel * 4) ^ ((lr & 7) << 4);
                    *(float*)((char*)R + byte) = acc[mf][nf][i] * s;
                }
            }
        }
        __syncthreads();

        // read + store: wave w owns rows [w*8, w*8+8); 1 full row per instr
#pragma unroll
        for (int j = 0; j < 8; ++j) {
            int lr = w * 8 + j;
            int byte = (lr * 1024 + lane * 16) ^ ((lr & 7) << 4);
            f32x4 v = *(const f32x4*)((const char*)R + byte);
            float* dst = out + obase + (size_t)(m0blk + p * 32 + lr) * NDIM
                       + n0blk + lane * 4;
            *(f32x4*)dst = v;
        }
        __syncthreads();   // pass-0 reads done before pass-1 overwrites
    }
}

extern "C" void kernel_launch(void* const* d_in, const int* in_sizes, int n_in,
                              void* d_out, int out_size, void* d_ws, size_t ws_size,
                              hipStream_t stream) {
    const float* x1 = (const float*)d_in[0];
    const float* x2 = (const float*)d_in[1];
    const float* c1 = (const float*)d_in[2];
    const float* c2 = (const float*)d_in[3];
    const int* lv   = (const int*)d_in[4];
    float* out = (float*)d_out;

    // workspace: qA codes 4MB @ 0, qB^T codes 4MB @ +4MB (needs ws >= 8MB)
    unsigned short* qA = (unsigned short*)d_ws;
    unsigned short* qB = qA + (size_t)BATCH * MDIM * KDIM;

    quant_both<<<QA_BLOCKS + BATCH * (NDIM / 64), 256, 0, stream>>>(
        x1, x2, qA, qB, c1, c2, lv);
    gemm_q<<<dim3(NDIM / 256, MDIM / 64, BATCH), 256, 0, stream>>>(
        qA, qB, c1, c2, lv, out);
}